// Round 6
// baseline (462.665 us; speedup 1.0000x reference)
//
#include <hip/hip_runtime.h>
#include <hip/hip_bf16.h>

typedef __hip_bfloat16 bf16;
typedef __attribute__((ext_vector_type(8))) short short8;   // 8 bf16 = 4 VGPRs (x32 A/B frag)
typedef __attribute__((ext_vector_type(4))) short short4v;  // 4 bf16 = 2 VGPRs (x16 A/B frag)
typedef __attribute__((ext_vector_type(4))) float f32x4;    // MFMA C/D frag

#define MFMA16(a, b, c) __builtin_amdgcn_mfma_f32_16x16x32_bf16((a), (b), (c), 0, 0, 0)

#if __has_builtin(__builtin_amdgcn_mfma_f32_16x16x16bf16_1k)
#define MFMA_PV(a, b, c) __builtin_amdgcn_mfma_f32_16x16x16bf16_1k((a), (b), (c), 0, 0, 0)
#elif __has_builtin(__builtin_amdgcn_mfma_f32_16x16x16_bf16)
#define MFMA_PV(a, b, c) __builtin_amdgcn_mfma_f32_16x16x16_bf16((a), (b), (c), 0, 0, 0)
#else
static __device__ __forceinline__ f32x4 mfma_pv_asm(short4v a, short4v b, f32x4 c) {
    f32x4 d;
    asm volatile("v_mfma_f32_16x16x16_bf16 %0, %1, %2, %3"
                 : "=&v"(d) : "v"(a), "v"(b), "v"(c));
    return d;
}
#define MFMA_PV(a, b, c) mfma_pv_asm((a), (b), (c))
#endif

static __device__ __forceinline__ void gload_lds16(const bf16* g, bf16* l) {
    __builtin_amdgcn_global_load_lds((const __attribute__((address_space(1))) void*)g,
                                     (__attribute__((address_space(3))) void*)l, 16, 0, 0);
}

// ---------------------------------------------------------------------------
// Kernel 1: fused prep — cast x -> bf16 (blocks 0..4095) and weight
// transpose+cast (blocks 4096..5119).
// ---------------------------------------------------------------------------
__global__ __launch_bounds__(256) void prep_kernel(
    const float* __restrict__ x,
    const float* __restrict__ wq, const float* __restrict__ wk,
    const float* __restrict__ wv, const float* __restrict__ wo,
    bf16* __restrict__ Xb, bf16* __restrict__ WqkvT, bf16* __restrict__ WoT) {
    __shared__ bf16 tile[64][65];
    int bid = blockIdx.x;
    if (bid < 4096) {
        int i = (bid * 256 + threadIdx.x) * 4;
        float4 v = *(const float4*)(x + i);
        union { bf16 h4[4]; uint2 u; } p;
        p.h4[0] = __float2bfloat16(v.x);
        p.h4[1] = __float2bfloat16(v.y);
        p.h4[2] = __float2bfloat16(v.z);
        p.h4[3] = __float2bfloat16(v.w);
        *(uint2*)(Xb + i) = p.u;
        return;
    }
    int t2 = bid - 4096;
    int mat = t2 >> 8;
    int t   = t2 & 255;
    int tn  = t >> 4, tk = t & 15;
    const float* src = (mat == 0) ? wq : (mat == 1) ? wk : (mat == 2) ? wv : wo;
    bf16* dst = (mat < 3) ? (WqkvT + (size_t)mat * 1024 * 1024) : WoT;
    int tx = threadIdx.x & 63, ty = threadIdx.x >> 6;
    int k0 = tk * 64, n0 = tn * 64;
#pragma unroll
    for (int p = 0; p < 16; ++p) {
        int r = p * 4 + ty;
        tile[r][tx] = __float2bfloat16(src[(size_t)(k0 + r) * 1024 + n0 + tx]);
    }
    __syncthreads();
#pragma unroll
    for (int p = 0; p < 16; ++p) {
        int r = p * 4 + ty;
        dst[(size_t)(n0 + r) * 1024 + k0 + tx] = tile[tx][r];
    }
}

// ---------------------------------------------------------------------------
// Kernel 2: GEMM1  QKV = Xb @ WqkvT^T, global_load_lds staging.
// Q columns (bn<8) are PRESCALED by 0.125*log2(e) for the attn softmax.
// ---------------------------------------------------------------------------
__global__ __launch_bounds__(256) void gemm_qkv_kernel(
    const bf16* __restrict__ A, const bf16* __restrict__ Bt,
    bf16* __restrict__ QK, bf16* __restrict__ Vt) {
    const int K = 1024;
    int bm = blockIdx.x, bn = blockIdx.y;
    __shared__ bf16 As[128 * 32];
    __shared__ bf16 Bs[128 * 32];
    int tid = threadIdx.x;
    int lane = tid & 63, w = tid >> 6;
    int wm = (w >> 1) * 64, wn = (w & 1) * 64;
    int q4 = lane >> 4, li = lane & 15;
    int srow = tid >> 2, sc = (tid & 3) * 8;

    const bf16* Ag = A + (size_t)(bm * 128 + srow) * K + sc;
    const bf16* Bg = Bt + (size_t)(bn * 128 + srow) * K + sc;
    bf16* Asl = As + tid * 8;
    bf16* Asl2 = As + 2048 + tid * 8;
    bf16* Bsl = Bs + tid * 8;
    bf16* Bsl2 = Bs + 2048 + tid * 8;

    f32x4 acc[4][4];
#pragma unroll
    for (int mt = 0; mt < 4; ++mt)
#pragma unroll
        for (int nt = 0; nt < 4; ++nt) acc[mt][nt] = (f32x4){0.f, 0.f, 0.f, 0.f};

    for (int k0 = 0; k0 < K; k0 += 32) {
        __syncthreads();
        gload_lds16(Ag + k0, Asl);
        gload_lds16(Ag + 64 * K + k0, Asl2);
        gload_lds16(Bg + k0, Bsl);
        gload_lds16(Bg + 64 * K + k0, Bsl2);
        __syncthreads();
        short8 af[4], bfb[4];
#pragma unroll
        for (int mt = 0; mt < 4; ++mt)
            af[mt] = *(const short8*)(As + (wm + mt * 16 + li) * 32 + q4 * 8);
#pragma unroll
        for (int nt = 0; nt < 4; ++nt)
            bfb[nt] = *(const short8*)(Bs + (wn + nt * 16 + li) * 32 + q4 * 8);
#pragma unroll
        for (int mt = 0; mt < 4; ++mt)
#pragma unroll
            for (int nt = 0; nt < 4; ++nt)
                acc[mt][nt] = MFMA16(af[mt], bfb[nt], acc[mt][nt]);
    }

    int rowb = bm * 128 + wm;
    if (bn < 16) {
        float qs = (bn < 8) ? 0.1803368801111244f : 1.0f;   // 0.125*log2(e) on Q
#pragma unroll
        for (int mt = 0; mt < 4; ++mt) {
#pragma unroll
            for (int nt = 0; nt < 4; ++nt) {
                int col = bn * 128 + wn + nt * 16 + li;
#pragma unroll
                for (int r = 0; r < 4; ++r) {
                    int row = rowb + mt * 16 + q4 * 4 + r;
                    QK[(size_t)row * 2048 + col] = __float2bfloat16(acc[mt][nt][r] * qs);
                }
            }
        }
    } else {
#pragma unroll
        for (int mt = 0; mt < 4; ++mt) {
            int sbase = rowb + mt * 16 + q4 * 4;
            int b = sbase >> 11, s = sbase & 2047;
#pragma unroll
            for (int nt = 0; nt < 4; ++nt) {
                int n = bn * 128 + wn + nt * 16 + li - 2048;
                int h = n >> 6, d = n & 63;
                union { bf16 h4[4]; uint2 u; } pk;
#pragma unroll
                for (int r = 0; r < 4; ++r) pk.h4[r] = __float2bfloat16(acc[mt][nt][r]);
                *(uint2*)(Vt + (size_t)((b * 16 + h) * 64 + d) * 2048 + s) = pk.u;
            }
        }
    }
}

// ---------------------------------------------------------------------------
// Kernel 3: flash attention, j-split waves + dbuf, SPLIT-J work units.
// Chunks of <=16 j-tiles; max-free softmax => chunk partials combine
// ADDITIVELY. Second arrival (atomic ticket) combines + normalizes.
// Ticket order guarantees no deadlock: ticket 1 implies partner finished.
// ---------------------------------------------------------------------------
__global__ __launch_bounds__(256, 4) void attn_kernel(
    const bf16* __restrict__ QK, const bf16* __restrict__ Vt,
    const float* __restrict__ x, const float* __restrict__ gch,
    bf16* __restrict__ AO, int* __restrict__ cnt, int* __restrict__ done,
    char* __restrict__ part) {
    const int S = 2048;
    // decode work item: [0,128) h0 chunks; [128,1088) causal ti>=16 chunks
    // (desc ti); [1088,1568) causal ti<16 single-chunk (desc ti).
    int idx = blockIdx.x;
    int ti, h, b, jt0, jt1, sid;
    if (idx < 128) {
        int u = idx >> 1, c = idx & 1;
        h = 0; b = u & 1; ti = u >> 1;
        jt0 = c * 16; jt1 = c ? 32 : 16;
        sid = u;
    } else if (idx < 1088) {
        int v = idx - 128;
        ti = 31 - v / 60;
        int g = v % 60;
        int hb = g >> 1, c = g & 1;
        h = 1 + (hb >> 1); b = hb & 1;
        jt0 = c ? 16 : 0; jt1 = c ? (ti + 1) : 16;
        sid = 64 + (ti - 16) * 30 + hb;
    } else {
        int v = idx - 1088;
        ti = 15 - v / 30;
        int g = v % 30;
        h = 1 + (g >> 1); b = g & 1;
        jt0 = 0; jt1 = ti + 1;
        sid = -1;
    }
    int i0 = ti * 64;
    int tid = threadIdx.x, lane = tid & 63, w = tid >> 6;
    int q4 = lane >> 4, li = lane & 15;

    __shared__ __align__(16) char smem[36864];
    __shared__ int ticket_sh;
    bf16* Ks0 = (bf16*)(smem);              // K tile [j][d], pitch 72
    bf16* Ks1 = (bf16*)(smem + 9216);
    bf16* Vs0 = (bf16*)(smem + 18432);      // V^T tile [d][j], pitch 72
    bf16* Vs1 = (bf16*)(smem + 27648);
    float* Ored  = (float*)(smem);          // [64][68] fp32, alias (post-loop)
    float* lsumB = (float*)(smem + 17408);  // [4][64] fp32, alias (post-loop)

    short8 qf[4][2];
#pragma unroll
    for (int it = 0; it < 4; ++it) {
        const bf16* qp = QK + (size_t)(b * S + i0 + it * 16 + li) * 2048 + h * 64 + q4 * 8;
        qf[it][0] = *(const short8*)(qp);
        qf[it][1] = *(const short8*)(qp + 32);
    }

    const float L2E = 1.4426950408889634f;
    float sl1 = exp2f(-0.5f * (float)(h + 1)) * L2E;
    const float slope0L = 0.70710678118654752f * L2E;

    float tgt[4]; int gcm[4];
    if (h == 0) {
#pragma unroll
        for (int it = 0; it < 4; ++it) {
            size_t ix = (size_t)(b * S + i0 + it * 16 + li);
            gcm[it] = gch[ix] > 0.5f ? 1 : 0;
            tgt[it] = x[ix * 1024 + 1008] + 1.0f + x[ix * 1024 + 1009];
        }
    } else {
#pragma unroll
        for (int it = 0; it < 4; ++it) { gcm[it] = 0; tgt[it] = 0.f; }
    }

    float lsum[4] = {0.f, 0.f, 0.f, 0.f};
    f32x4 o[4][4];
#pragma unroll
    for (int it = 0; it < 4; ++it)
#pragma unroll
        for (int dt = 0; dt < 4; ++dt) o[it][dt] = (f32x4){0.f, 0.f, 0.f, 0.f};

    int srow = tid >> 3, scv = (tid & 7) * 8;
    const bf16* Kg = QK + (size_t)(b * S + srow) * 2048 + 1024 + h * 64 + scv;
    const bf16* Vg = Vt + (size_t)((b * 16 + h) * 64 + srow) * 2048 + scv;

    int nt_ = jt1 - jt0;
    size_t g0 = (size_t)jt0 * 64;
    uint4 kv0 = *(const uint4*)(Kg + g0 * 2048);
    uint4 kv1 = *(const uint4*)(Kg + (g0 + 32) * 2048);
    uint4 vv0 = *(const uint4*)(Vg + g0);
    uint4 vv1 = *(const uint4*)(Vg + (size_t)32 * 2048 + g0);
    *(uint4*)(Ks0 + srow * 72 + scv) = kv0;
    *(uint4*)(Ks0 + (srow + 32) * 72 + scv) = kv1;
    *(uint4*)(Vs0 + srow * 72 + scv) = vv0;
    *(uint4*)(Vs0 + (srow + 32) * 72 + scv) = vv1;
    if (nt_ > 1) {
        kv0 = *(const uint4*)(Kg + (g0 + 64) * 2048);
        kv1 = *(const uint4*)(Kg + (g0 + 96) * 2048);
        vv0 = *(const uint4*)(Vg + g0 + 64);
        vv1 = *(const uint4*)(Vg + (size_t)32 * 2048 + g0 + 64);
    }
    __syncthreads();

    for (int t = 0; t < nt_; ++t) {
        const bf16* Kc = (t & 1) ? Ks1 : Ks0;
        const bf16* Vc = (t & 1) ? Vs1 : Vs0;
        if (t + 1 < nt_) {
            bf16* Kn = (t & 1) ? Ks0 : Ks1;
            bf16* Vn = (t & 1) ? Vs0 : Vs1;
            *(uint4*)(Kn + srow * 72 + scv) = kv0;
            *(uint4*)(Kn + (srow + 32) * 72 + scv) = kv1;
            *(uint4*)(Vn + srow * 72 + scv) = vv0;
            *(uint4*)(Vn + (srow + 32) * 72 + scv) = vv1;
            if (t + 2 < nt_) {
                size_t jn = (size_t)(jt0 + t + 2) * 64;
                kv0 = *(const uint4*)(Kg + jn * 2048);
                kv1 = *(const uint4*)(Kg + (jn + 32) * 2048);
                vv0 = *(const uint4*)(Vg + jn);
                vv1 = *(const uint4*)(Vg + (size_t)32 * 2048 + jn);
            }
        }

        int jt = jt0 + t;
        int j0 = jt * 64;
        short8 kf0 = *(const short8*)(Kc + (w * 16 + li) * 72 + q4 * 8);
        short8 kf1 = *(const short8*)(Kc + (w * 16 + li) * 72 + 32 + q4 * 8);
        f32x4 sA[4];
#pragma unroll
        for (int it = 0; it < 4; ++it) {
            f32x4 z = (f32x4){0.f, 0.f, 0.f, 0.f};
            z = MFMA16(kf0, qf[it][0], z);
            z = MFMA16(kf1, qf[it][1], z);
            sA[it] = z;
        }

        float jbase = (float)(j0 + w * 16 + q4 * 4);
        bool diag = (jt >= ti);
        short4v pf[4];
#pragma unroll
        for (int it = 0; it < 4; ++it) {
            float fi = (float)(i0 + it * 16 + li);
            float d0 = jbase - fi;
            union { bf16 hh[4]; short4v v; } pu;
#pragma unroll
            for (int r = 0; r < 4; ++r) {
                float dj = d0 + (float)r;
                float p;
                if (h == 0) {
                    float s = fmaf(sl1, dj, sA[it][r]);
                    float sg = -slope0L * fabsf(tgt[it] - (jbase + (float)r));
                    s = gcm[it] ? sg : s;
                    p = exp2f(s);
                    if (!gcm[it] && dj > 0.f) p = 0.f;
                } else {
                    float s = fmaf(sl1, dj, sA[it][r]);
                    p = exp2f(s);
                    if (diag && dj > 0.f) p = 0.f;
                }
                lsum[it] += p;
                pu.hh[r] = __float2bfloat16(p);
            }
            pf[it] = pu.v;
        }

#pragma unroll
        for (int dt = 0; dt < 4; ++dt) {
            short4v vf = *(const short4v*)(Vc + (dt * 16 + li) * 72 + w * 16 + q4 * 4);
#pragma unroll
            for (int it = 0; it < 4; ++it)
                o[it][dt] = MFMA_PV(pf[it], vf, o[it][dt]);
        }
        __syncthreads();
    }

#pragma unroll
    for (int it = 0; it < 4; ++it) {
        lsum[it] += __shfl_xor(lsum[it], 16, 64);
        lsum[it] += __shfl_xor(lsum[it], 32, 64);
    }
    if (lane < 16) {
#pragma unroll
        for (int it = 0; it < 4; ++it) lsumB[w * 64 + it * 16 + lane] = lsum[it];
    }

    __syncthreads();
    if (w == 0) {
#pragma unroll
        for (int it = 0; it < 4; ++it)
#pragma unroll
            for (int dt = 0; dt < 4; ++dt)
#pragma unroll
                for (int r = 0; r < 4; ++r)
                    Ored[(it * 16 + q4 * 4 + r) * 68 + dt * 16 + li] = o[it][dt][r];
    }
    __syncthreads();
    if (w == 1) {
#pragma unroll
        for (int it = 0; it < 4; ++it)
#pragma unroll
            for (int dt = 0; dt < 4; ++dt)
#pragma unroll
                for (int r = 0; r < 4; ++r)
                    Ored[(it * 16 + q4 * 4 + r) * 68 + dt * 16 + li] += o[it][dt][r];
    }
    __syncthreads();
    if (w == 2) {
#pragma unroll
        for (int it = 0; it < 4; ++it)
#pragma unroll
            for (int dt = 0; dt < 4; ++dt)
#pragma unroll
                for (int r = 0; r < 4; ++r)
                    Ored[(it * 16 + q4 * 4 + r) * 68 + dt * 16 + li] += o[it][dt][r];
    }
    __syncthreads();
    if (w == 3) {
#pragma unroll
        for (int it = 0; it < 4; ++it)
#pragma unroll
            for (int dt = 0; dt < 4; ++dt)
#pragma unroll
                for (int r = 0; r < 4; ++r)
                    Ored[(it * 16 + q4 * 4 + r) * 68 + dt * 16 + li] += o[it][dt][r];
    }
    __syncthreads();

    int i = tid >> 2, dseg = (tid & 3) * 16;
    float ls = lsumB[i] + lsumB[64 + i] + lsumB[128 + i] + lsumB[192 + i];

    if (sid < 0) {
        float inv = 1.0f / ls;
        bf16* dst = AO + (size_t)(b * S + i0 + i) * 1024 + h * 64 + dseg;
        union { bf16 hh[16]; uint4 u[2]; } ou;
#pragma unroll
        for (int c = 0; c < 16; ++c)
            ou.hh[c] = __float2bfloat16(Ored[i * 68 + dseg + c] * inv);
        *(uint4*)(dst) = ou.u[0];
        *(uint4*)(dst + 8) = ou.u[1];
        return;
    }

    // split path: slot = [bf16 O 8192][fp32 lsum 256][pad] = 8704 B
    char* slot = part + (size_t)sid * 8704;
    bf16* Opart = (bf16*)slot;
    float* Lpart = (float*)(slot + 8192);

    if (tid == 0) ticket_sh = atomicAdd(&cnt[sid], 1);
    __syncthreads();
    int ticket = ticket_sh;

    if (ticket == 0) {
        union { bf16 hh[16]; uint4 u[2]; } pu;
#pragma unroll
        for (int c = 0; c < 16; ++c)
            pu.hh[c] = __float2bfloat16(Ored[i * 68 + dseg + c]);
        *(uint4*)(Opart + i * 64 + dseg) = pu.u[0];
        *(uint4*)(Opart + i * 64 + dseg + 8) = pu.u[1];
        if ((tid & 3) == 0) Lpart[i] = ls;
        __threadfence();
        __syncthreads();
        if (tid == 0)
            __hip_atomic_store(&done[sid], 1, __ATOMIC_RELEASE, __HIP_MEMORY_SCOPE_AGENT);
    } else {
        if (tid == 0) {
            while (__hip_atomic_load(&done[sid], __ATOMIC_ACQUIRE, __HIP_MEMORY_SCOPE_AGENT) == 0)
                __builtin_amdgcn_s_sleep(8);
        }
        __syncthreads();
        float pls = Lpart[i];
        float inv = 1.0f / (ls + pls);
        bf16* dst = AO + (size_t)(b * S + i0 + i) * 1024 + h * 64 + dseg;
        union { bf16 hh[16]; uint4 u[2]; } pv;
        pv.u[0] = *(const uint4*)(Opart + i * 64 + dseg);
        pv.u[1] = *(const uint4*)(Opart + i * 64 + dseg + 8);
        union { bf16 hh[16]; uint4 u[2]; } ou;
#pragma unroll
        for (int c = 0; c < 16; ++c) {
            float v = Ored[i * 68 + dseg + c] + __bfloat162float(pv.hh[c]);
            ou.hh[c] = __float2bfloat16(v * inv);
        }
        *(uint4*)(dst) = ou.u[0];
        *(uint4*)(dst + 8) = ou.u[1];
    }
}

// ---------------------------------------------------------------------------
// Kernel 4: GEMM2  out = x + AO @ WoT^T (fp32 out) + fused I/O fixups
// ---------------------------------------------------------------------------
__global__ __launch_bounds__(256) void gemm_out_kernel(
    const bf16* __restrict__ A, const bf16* __restrict__ Bt,
    const float* __restrict__ x, const float* __restrict__ gch,
    const float* __restrict__ pch, float* __restrict__ out) {
    const int K = 1024;
    int bm = blockIdx.x, bn = blockIdx.y;
    __shared__ bf16 As[128 * 32];
    __shared__ bf16 Bs[128 * 32];
    int tid = threadIdx.x;
    int lane = tid & 63, w = tid >> 6;
    int wm = (w >> 1) * 64, wn = (w & 1) * 64;
    int q4 = lane >> 4, li = lane & 15;
    int srow = tid >> 2, sc = (tid & 3) * 8;

    const bf16* Ag = A + (size_t)(bm * 128 + srow) * K + sc;
    const bf16* Bg = Bt + (size_t)(bn * 128 + srow) * K + sc;
    bf16* Asl = As + tid * 8;
    bf16* Asl2 = As + 2048 + tid * 8;
    bf16* Bsl = Bs + tid * 8;
    bf16* Bsl2 = Bs + 2048 + tid * 8;

    f32x4 acc[4][4];
#pragma unroll
    for (int mt = 0; mt < 4; ++mt)
#pragma unroll
        for (int nt = 0; nt < 4; ++nt) acc[mt][nt] = (f32x4){0.f, 0.f, 0.f, 0.f};

    for (int k0 = 0; k0 < K; k0 += 32) {
        __syncthreads();
        gload_lds16(Ag + k0, Asl);
        gload_lds16(Ag + 64 * K + k0, Asl2);
        gload_lds16(Bg + k0, Bsl);
        gload_lds16(Bg + 64 * K + k0, Bsl2);
        __syncthreads();
        short8 af[4], bfb[4];
#pragma unroll
        for (int mt = 0; mt < 4; ++mt)
            af[mt] = *(const short8*)(As + (wm + mt * 16 + li) * 32 + q4 * 8);
#pragma unroll
        for (int nt = 0; nt < 4; ++nt)
            bfb[nt] = *(const short8*)(Bs + (wn + nt * 16 + li) * 32 + q4 * 8);
#pragma unroll
        for (int mt = 0; mt < 4; ++mt)
#pragma unroll
            for (int nt = 0; nt < 4; ++nt)
                acc[mt][nt] = MFMA16(af[mt], bfb[nt], acc[mt][nt]);
    }

#pragma unroll
    for (int mt = 0; mt < 4; ++mt) {
#pragma unroll
        for (int nt = 0; nt < 4; ++nt) {
            int col = bn * 128 + wn + nt * 16 + li;
#pragma unroll
            for (int r = 0; r < 4; ++r) {
                int row = bm * 128 + wm + mt * 16 + q4 * 4 + r;
                size_t idx = (size_t)row * 1024 + col;
                float v = x[idx] + acc[mt][nt][r];
                if (col == 1009) v += gch[row];
                else if (col == 1011) v += pch[row];
                else if (col == 1021) v = pch[row];
                out[idx] = v;
            }
        }
    }
}

// ---------------------------------------------------------------------------
extern "C" void kernel_launch(void* const* d_in, const int* in_sizes, int n_in,
                              void* d_out, int out_size, void* d_ws, size_t ws_size,
                              hipStream_t stream) {
    (void)in_sizes; (void)n_in; (void)out_size; (void)ws_size;
    const float* x   = (const float*)d_in[0];
    const float* gch = (const float*)d_in[1];
    const float* pch = (const float*)d_in[2];
    const float* wq  = (const float*)d_in[3];
    const float* wk  = (const float*)d_in[4];
    const float* wv  = (const float*)d_in[5];
    const float* wo  = (const float*)d_in[6];
    float* out = (float*)d_out;

    char* ws = (char*)d_ws;
    bf16* Xb    = (bf16*)(ws);
    bf16* WqkvT = (bf16*)(ws + (size_t)( 8 << 20));
    bf16* WoT   = (bf16*)(ws + (size_t)(14 << 20));
    bf16* QK    = (bf16*)(ws + (size_t)(16 << 20));
    bf16* Vt    = (bf16*)(ws + (size_t)(32 << 20));
    bf16* AO    = Xb;  // Xb dead after gemm_qkv
    // split-combine scratch overlays WqkvT (dead after gemm_qkv):
    int*  cnt  = (int*)(ws + (size_t)(8 << 20));
    int*  done = cnt + 1024;
    char* part = ws + (size_t)(8 << 20) + 16384;   // 544 slots x 8704 B

    prep_kernel<<<5120, 256, 0, stream>>>(x, wq, wk, wv, wo, Xb, WqkvT, WoT);
    gemm_qkv_kernel<<<dim3(32, 24), 256, 0, stream>>>(Xb, WqkvT, QK, Vt);
    hipMemsetAsync(ws + (size_t)(8 << 20), 0, 8192, stream);   // zero cnt+done
    attn_kernel<<<1568, 256, 0, stream>>>(QK, Vt, x, gch, AO, cnt, done, part);
    gemm_out_kernel<<<dim3(32, 8), 256, 0, stream>>>(AO, WoT, x, gch, pch, out);
}